// Round 1
// baseline (1196.047 us; speedup 1.0000x reference)
//
#include <hip/hip_runtime.h>
#include <hip/hip_bf16.h>

typedef __hip_bfloat16 bf16;
typedef __attribute__((ext_vector_type(8))) __bf16 bf16x8;
typedef __attribute__((ext_vector_type(4))) float f32x4;

#define BM 128
#define BN 128
#define BK 64

typedef const __attribute__((address_space(1))) void gvoid;
typedef __attribute__((address_space(3))) void lvoid;

// NT GEMM: C[m,n] = sum_k A[m,k] * B[n,k]   (both operands row-major, K contiguous)
// MODE 0: C bf16 = acc + bias[z*sBiasZ + m]                  (v proj)
// MODE 1: C bf16 = acc + bias[n]                             (qk proj)
// MODE 2: C f32  = acc                                       (energy)
// MODE 3: C bf16 = gamma[z]*acc + xt[m*ldxt+n]               (o -> heads_t)
// MODE 4: C bf16 = relu(acc + bias[n])                       (fc1)
// MODE 5: out f32 scatter: out[(n*8+h)*1024+t] = relu(acc+bias[n]) + xf[...]  (fc2+final)
template<int MODE>
__global__ __launch_bounds__(256)
void gemm_nt(const bf16* __restrict__ A, long lda, long sAz,
             const bf16* __restrict__ B, long ldb, long sBz,
             void* __restrict__ Cv, long ldc, long sCz,
             int K,
             const float* __restrict__ bias, long sBiasZ,
             const float* __restrict__ gamma,
             const bf16* __restrict__ xt, long ldxt,
             const float* __restrict__ xf)
{
    __shared__ bf16 As[BM * BK];
    __shared__ bf16 Bs[BN * BK];
    const int z = blockIdx.z;
    const bf16* Ab = A + (long)z * sAz + (long)blockIdx.y * BM * lda;
    const bf16* Bb = B + (long)z * sBz + (long)blockIdx.x * BN * ldb;
    const int tid  = threadIdx.x;
    const int wave = tid >> 6, lane = tid & 63;
    const int col  = lane & 15, quad = lane >> 4;
    const int wm = (wave & 1) * 64, wn = (wave >> 1) * 64;

    f32x4 acc[4][4] = {};

    for (int k0 = 0; k0 < K; k0 += BK) {
        __syncthreads();
        // stage 128x64 bf16 tiles of A and B; XOR-swizzle 16B chunks by (row&7)
        #pragma unroll
        for (int i = 0; i < 4; ++i) {
            int cbase = i * 256 + wave * 64;     // wave-uniform chunk base
            int c = cbase + lane;                // 16B chunk id 0..1023
            int m = c >> 3;                      // tile row 0..127
            int j = c & 7;                       // chunk slot in row
            int kch = ((j ^ (m & 7)) << 3);      // swizzled k offset (elements)
            __builtin_amdgcn_global_load_lds(
                (gvoid*)(Ab + (long)m * lda + k0 + kch),
                (lvoid*)(As + cbase * 8), 16, 0, 0);
            __builtin_amdgcn_global_load_lds(
                (gvoid*)(Bb + (long)m * ldb + k0 + kch),
                (lvoid*)(Bs + cbase * 8), 16, 0, 0);
        }
        __syncthreads();
        #pragma unroll
        for (int kk = 0; kk < BK; kk += 32) {
            bf16x8 af[4], bfr[4];
            int kq = (kk >> 3) + quad;
            #pragma unroll
            for (int mi = 0; mi < 4; ++mi) {
                int m = wm + mi * 16 + col;
                af[mi] = *(const bf16x8*)(As + m * BK + ((kq ^ (m & 7)) << 3));
            }
            #pragma unroll
            for (int ni = 0; ni < 4; ++ni) {
                int n = wn + ni * 16 + col;
                bfr[ni] = *(const bf16x8*)(Bs + n * BK + ((kq ^ (n & 7)) << 3));
            }
            #pragma unroll
            for (int mi = 0; mi < 4; ++mi)
                #pragma unroll
                for (int ni = 0; ni < 4; ++ni)
                    acc[mi][ni] = __builtin_amdgcn_mfma_f32_16x16x32_bf16(
                        af[mi], bfr[ni], acc[mi][ni], 0, 0, 0);
        }
    }

    const long m0 = (long)blockIdx.y * BM + wm;
    const long n0 = (long)blockIdx.x * BN + wn;
    float g = 0.f;
    if (MODE == 3) g = gamma[z];
    #pragma unroll
    for (int mi = 0; mi < 4; ++mi) {
        #pragma unroll
        for (int ni = 0; ni < 4; ++ni) {
            long mb = m0 + mi * 16 + quad * 4;
            long n  = n0 + ni * 16 + col;
            #pragma unroll
            for (int r = 0; r < 4; ++r) {
                long m = mb + r;
                float v = acc[mi][ni][r];
                if constexpr (MODE == 0) {
                    v += bias[z * sBiasZ + m];
                    ((bf16*)Cv)[z * sCz + m * ldc + n] = __float2bfloat16(v);
                } else if constexpr (MODE == 1) {
                    v += bias[n];
                    ((bf16*)Cv)[z * sCz + m * ldc + n] = __float2bfloat16(v);
                } else if constexpr (MODE == 2) {
                    ((float*)Cv)[z * sCz + m * ldc + n] = v;
                } else if constexpr (MODE == 3) {
                    float xv = __bfloat162float(xt[m * ldxt + n]);
                    ((bf16*)Cv)[z * sCz + m * ldc + n] = __float2bfloat16(g * v + xv);
                } else if constexpr (MODE == 4) {
                    v += bias[n];
                    v = v > 0.f ? v : 0.f;
                    ((bf16*)Cv)[z * sCz + m * ldc + n] = __float2bfloat16(v);
                } else {  // MODE 5
                    v += bias[n];
                    v = v > 0.f ? v : 0.f;
                    long h = m >> 10, t = m & 1023;
                    long oi = (n * 8 + h) * 1024 + t;
                    ((float*)Cv)[oi] = v + xf[oi];
                }
            }
        }
    }
}

// x (B,C,T) f32 -> xt (B,T,C) bf16, 32x32 LDS tiles
__global__ __launch_bounds__(256)
void transpose_cast_x(const float* __restrict__ x, bf16* __restrict__ xt)
{
    __shared__ float tile[32][33];
    int b = blockIdx.z;
    int c0 = blockIdx.y * 32, t0 = blockIdx.x * 32;
    int tx = threadIdx.x & 31, ty = threadIdx.x >> 5;  // ty 0..7
    const float* xb = x + (long)b * 1024 * 1024;
    #pragma unroll
    for (int i = 0; i < 4; ++i) {
        int c = ty + i * 8;
        tile[c][tx] = xb[(long)(c0 + c) * 1024 + t0 + tx];
    }
    __syncthreads();
    bf16* xtb = xt + (long)b * 1024 * 1024;
    #pragma unroll
    for (int i = 0; i < 4; ++i) {
        int t = ty + i * 8;
        xtb[(long)(t0 + t) * 1024 + c0 + tx] = __float2bfloat16(tile[tx][t]);
    }
}

__global__ __launch_bounds__(256)
void cast_f2b(const float* __restrict__ in, bf16* __restrict__ out, long n)
{
    long i = (long)blockIdx.x * 256 + threadIdx.x;
    long stride = (long)gridDim.x * 256;
    for (; i < n; i += stride) out[i] = __float2bfloat16(in[i]);
}

// Build stacked qk weight (2048 x 1024 bf16): row h*256 + {0..127 -> Wq[h], 128..255 -> Wk[h]}
__global__ __launch_bounds__(256)
void build_wqk(const float* __restrict__ Wq, const float* __restrict__ Wk,
               const float* __restrict__ bq, const float* __restrict__ bk,
               bf16* __restrict__ Wqk, float* __restrict__ biasqk)
{
    long i = (long)blockIdx.x * 256 + threadIdx.x;   // 2048*1024 total
    long r = i >> 10, c = i & 1023;
    long h = r >> 8, rr = r & 255;
    float v = (rr < 128) ? Wq[(h * 128 + rr) * 1024 + c]
                         : Wk[(h * 128 + (rr - 128)) * 1024 + c];
    Wqk[i] = __float2bfloat16(v);
    if (c == 0)
        biasqk[r] = (rr < 128) ? bq[h * 128 + rr] : bk[h * 128 + rr - 128];
}

// one block per row: softmax over 1024 fp32 logits -> bf16
__global__ __launch_bounds__(256)
void softmax_rows(const float* __restrict__ E, bf16* __restrict__ A)
{
    long row = blockIdx.x;
    const float* e = E + row * 1024;
    bf16* a = A + row * 1024;
    int tid = threadIdx.x;
    int wave = tid >> 6, lane = tid & 63;
    float v[4];
    float mx = -1e30f;
    #pragma unroll
    for (int i = 0; i < 4; ++i) { v[i] = e[tid + i * 256]; mx = fmaxf(mx, v[i]); }
    #pragma unroll
    for (int off = 32; off; off >>= 1) mx = fmaxf(mx, __shfl_xor(mx, off, 64));
    __shared__ float red[4], red2[4];
    if (lane == 0) red[wave] = mx;
    __syncthreads();
    mx = fmaxf(fmaxf(red[0], red[1]), fmaxf(red[2], red[3]));
    float s = 0.f;
    #pragma unroll
    for (int i = 0; i < 4; ++i) { v[i] = __expf(v[i] - mx); s += v[i]; }
    #pragma unroll
    for (int off = 32; off; off >>= 1) s += __shfl_xor(s, off, 64);
    if (lane == 0) red2[wave] = s;
    __syncthreads();
    s = red2[0] + red2[1] + red2[2] + red2[3];
    float inv = 1.0f / s;
    #pragma unroll
    for (int i = 0; i < 4; ++i) a[tid + i * 256] = __float2bfloat16(v[i] * inv);
}

extern "C" void kernel_launch(void* const* d_in, const int* in_sizes, int n_in,
                              void* d_out, int out_size, void* d_ws, size_t ws_size,
                              hipStream_t stream)
{
    const float* x     = (const float*)d_in[0];
    const float* Wq    = (const float*)d_in[1];
    const float* bq    = (const float*)d_in[2];
    const float* Wk    = (const float*)d_in[3];
    const float* bk    = (const float*)d_in[4];
    const float* Wv    = (const float*)d_in[5];
    const float* bv    = (const float*)d_in[6];
    const float* gamma = (const float*)d_in[7];
    const float* W1    = (const float*)d_in[8];
    const float* b1    = (const float*)d_in[9];
    const float* W2    = (const float*)d_in[10];
    const float* b2    = (const float*)d_in[11];
    float* out = (float*)d_out;

    char* p = (char*)d_ws;
    auto alloc = [&](size_t bytes) { char* r = p; p += (bytes + 255) & ~(size_t)255; return r; };
    bf16*  xt   = (bf16*)alloc(8ll * 1024 * 1024 * 2);   // (B,T,C)
    bf16*  Wqk  = (bf16*)alloc(2048ll * 1024 * 2);
    bf16*  Wvb  = (bf16*)alloc(8192ll * 1024 * 2);       // (H*1024, 1024)
    bf16*  W1b  = (bf16*)alloc(128ll * 1024 * 2);
    bf16*  W2b  = (bf16*)alloc(128ll * 128 * 2);
    float* bqk  = (float*)alloc(2048 * 4);
    bf16*  qkt  = (bf16*)alloc(1024ll * 2048 * 2);       // per-b (t, h*256+o)
    bf16*  vbuf = (bf16*)alloc(8ll * 1024 * 1024 * 2);   // per-b (h, c, s)
    float* Ebuf = (float*)alloc(8ll * 1024 * 1024 * 4);  // per-b (h, t, s)
    bf16*  attn = (bf16*)alloc(8ll * 1024 * 1024 * 2);   // per-b (h, t, s)
    bf16*  ot   = (bf16*)alloc(8ll * 1024 * 1024 * 2);   // per-b heads_t (h, t, c)
    bf16*  y1   = (bf16*)alloc(8192ll * 128 * 2);        // per-b (h*T+t, 128)

    dim3 blk(256);
    transpose_cast_x<<<dim3(32, 32, 8), blk, 0, stream>>>(x, xt);
    build_wqk<<<8192, blk, 0, stream>>>(Wq, Wk, bq, bk, Wqk, bqk);
    cast_f2b<<<4096, blk, 0, stream>>>(Wv, Wvb, 8192ll * 1024);
    cast_f2b<<<512, blk, 0, stream>>>(W1, W1b, 128 * 1024);
    cast_f2b<<<64, blk, 0, stream>>>(W2, W2b, 128 * 128);

    for (int b = 0; b < 8; ++b) {
        const bf16* xtb = xt + (long)b * 1024 * 1024;
        // qk_t(t, h*256+o) = xt(t,c) . Wqk(n,c)^T + bias_qk[n]   M=1024 N=2048 K=1024
        gemm_nt<1><<<dim3(16, 8, 1), blk, 0, stream>>>(
            xtb, 1024, 0, Wqk, 1024, 0, qkt, 2048, 0, 1024,
            bqk, 0, nullptr, nullptr, 0, nullptr);
        // v(h; c, s) = Wv[h](c,ci) . xt(s,ci)^T + bv[h,c]        M=1024 N=1024 K=1024, z=h
        gemm_nt<0><<<dim3(8, 8, 8), blk, 0, stream>>>(
            Wvb, 1024, 1024ll * 1024, xtb, 1024, 0, vbuf, 1024, 1024ll * 1024, 1024,
            bv, 1024, nullptr, nullptr, 0, nullptr);
        // E(h; t, s) = q_t(t,o) . k_t(s,o)^T                     M=1024 N=1024 K=128, z=h
        gemm_nt<2><<<dim3(8, 8, 8), blk, 0, stream>>>(
            qkt, 2048, 256, qkt + 128, 2048, 256, Ebuf, 1024, 1024ll * 1024, 128,
            nullptr, 0, nullptr, nullptr, 0, nullptr);
        softmax_rows<<<8192, blk, 0, stream>>>(Ebuf, attn);
        // heads_t(h; t, c) = gamma[h] * (attn(t,s) . v(c,s)^T) + xt(t,c)   K=1024, z=h
        gemm_nt<3><<<dim3(8, 8, 8), blk, 0, stream>>>(
            attn, 1024, 1024ll * 1024, vbuf, 1024, 1024ll * 1024, ot, 1024, 1024ll * 1024, 1024,
            nullptr, 0, gamma, xtb, 1024, nullptr);
        // y1(ht, j) = relu(heads_t(ht,c) . W1(j,c)^T + b1[j])    M=8192 N=128 K=1024
        gemm_nt<4><<<dim3(1, 64, 1), blk, 0, stream>>>(
            ot, 1024, 0, W1b, 1024, 0, y1, 128, 0, 1024,
            b1, 0, nullptr, nullptr, 0, nullptr);
        // out[b,(d*8+h),t] = relu(y1(ht,j) . W2(d,j)^T + b2[d]) + x[b,(d*8+h),t]
        gemm_nt<5><<<dim3(1, 64, 1), blk, 0, stream>>>(
            y1, 128, 0, W2b, 128, 0, out + (long)b * 1024 * 1024, 128, 0, 128,
            b2, 0, nullptr, nullptr, 0, x + (long)b * 1024 * 1024);
    }
}

// Round 3
// 866.761 us; speedup vs baseline: 1.3799x; 1.3799x over previous
//
#include <hip/hip_runtime.h>
#include <hip/hip_bf16.h>

typedef __hip_bfloat16 bf16;
typedef __attribute__((ext_vector_type(8))) __bf16 bf16x8;
typedef __attribute__((ext_vector_type(4))) float f32x4;

#define BM 128
#define BN 128

typedef const __attribute__((address_space(1))) void gvoid;
typedef __attribute__((address_space(3))) void lvoid;

// NT GEMM: C[m,n] = sum_k A[m,k] * B[n,k]   (both row-major, K contiguous)
// z decomposes as zb = z>>3 (local batch), zh = z&7 (head).
// MODE 0: C bf16 = acc + bias[zh*sBiasZ + m]                 (v proj)
// MODE 1: C bf16 = acc + bias[n]                             (qk proj)
// MODE 2: C f32  = acc                                       (energy)
// MODE 3: C bf16 = gamma[zh]*acc + xt[zb*1M + m*ldxt + n]    (o -> heads_t)
// MODE 4: C bf16 = relu(acc + bias[n])                       (fc1)
// MODE 5: out f32 scatter + residual (m is GLOBAL row b*8192+h*1024+t)
template<int MODE, int TBK>
__global__ __launch_bounds__(256)
void gemm_nt(const bf16* __restrict__ A, long lda, long sAb, long sAh,
             const bf16* __restrict__ B, long ldb, long sBb, long sBh,
             void* __restrict__ Cv, long ldc, long sCb, long sCh,
             int K,
             const float* __restrict__ bias, long sBiasZ,
             const float* __restrict__ gamma,
             const bf16* __restrict__ xt, long ldxt,
             const float* __restrict__ xf)
{
    __shared__ bf16 As[BM * TBK];
    __shared__ bf16 Bs[BN * TBK];
    const int z = blockIdx.z;
    const int zb = z >> 3, zh = z & 7;
    const bf16* Ab = A + (long)zb * sAb + (long)zh * sAh + (long)blockIdx.y * BM * lda;
    const bf16* Bb = B + (long)zb * sBb + (long)zh * sBh + (long)blockIdx.x * BN * ldb;
    const int tid  = threadIdx.x;
    const int wave = tid >> 6, lane = tid & 63;
    const int col  = lane & 15, quad = lane >> 4;
    const int wm = (wave & 1) * 64, wn = (wave >> 1) * 64;
    constexpr int CPR = TBK / 8;            // 16B chunks per row

    f32x4 acc[4][4] = {};

    for (int k0 = 0; k0 < K; k0 += TBK) {
        __syncthreads();
        #pragma unroll
        for (int i = 0; i < TBK / 16; ++i) {
            int cbase = i * 256 + wave * 64;     // wave-uniform chunk base
            int c = cbase + lane;                // chunk id
            int m = c / CPR;                     // tile row
            int j = c % CPR;                     // chunk slot in row
            int kch = ((j ^ (m & 7)) << 3);      // swizzled k offset (elements)
            __builtin_amdgcn_global_load_lds(
                (gvoid*)(Ab + (long)m * lda + k0 + kch),
                (lvoid*)(As + cbase * 8), 16, 0, 0);
            __builtin_amdgcn_global_load_lds(
                (gvoid*)(Bb + (long)m * ldb + k0 + kch),
                (lvoid*)(Bs + cbase * 8), 16, 0, 0);
        }
        __syncthreads();
        #pragma unroll
        for (int kk = 0; kk < TBK; kk += 32) {
            bf16x8 af[4], bfr[4];
            int kq = (kk >> 3) + quad;
            #pragma unroll
            for (int mi = 0; mi < 4; ++mi) {
                int m = wm + mi * 16 + col;
                af[mi] = *(const bf16x8*)(As + m * TBK + ((kq ^ (m & 7)) << 3));
            }
            #pragma unroll
            for (int ni = 0; ni < 4; ++ni) {
                int n = wn + ni * 16 + col;
                bfr[ni] = *(const bf16x8*)(Bs + n * TBK + ((kq ^ (n & 7)) << 3));
            }
            #pragma unroll
            for (int mi = 0; mi < 4; ++mi)
                #pragma unroll
                for (int ni = 0; ni < 4; ++ni)
                    acc[mi][ni] = __builtin_amdgcn_mfma_f32_16x16x32_bf16(
                        af[mi], bfr[ni], acc[mi][ni], 0, 0, 0);
        }
    }

    const long m0 = (long)blockIdx.y * BM + wm;
    const long n0 = (long)blockIdx.x * BN + wn;
    float g = 0.f;
    if (MODE == 3) g = gamma[zh];
    #pragma unroll
    for (int mi = 0; mi < 4; ++mi) {
        #pragma unroll
        for (int ni = 0; ni < 4; ++ni) {
            long mb = m0 + mi * 16 + quad * 4;
            long n  = n0 + ni * 16 + col;
            #pragma unroll
            for (int r = 0; r < 4; ++r) {
                long m = mb + r;
                float v = acc[mi][ni][r];
                if constexpr (MODE == 0) {
                    v += bias[zh * sBiasZ + m];
                    ((bf16*)Cv)[(long)zb * sCb + (long)zh * sCh + m * ldc + n] = __float2bfloat16(v);
                } else if constexpr (MODE == 1) {
                    v += bias[n];
                    ((bf16*)Cv)[m * ldc + n] = __float2bfloat16(v);
                } else if constexpr (MODE == 2) {
                    ((float*)Cv)[(long)zb * sCb + (long)zh * sCh + m * ldc + n] = v;
                } else if constexpr (MODE == 3) {
                    float xv = __bfloat162float(xt[(long)zb * 1048576 + m * ldxt + n]);
                    ((bf16*)Cv)[(long)zb * sCb + (long)zh * sCh + m * ldc + n] = __float2bfloat16(g * v + xv);
                } else if constexpr (MODE == 4) {
                    v += bias[n];
                    v = v > 0.f ? v : 0.f;
                    ((bf16*)Cv)[m * ldc + n] = __float2bfloat16(v);
                } else {  // MODE 5: m global = b*8192 + h*1024 + t
                    v += bias[n];
                    v = v > 0.f ? v : 0.f;
                    long bb = m >> 13, h = (m >> 10) & 7, t = m & 1023;
                    long oi = bb * 1048576 + (n * 8 + h) * 1024 + t;
                    ((float*)Cv)[oi] = v + xf[oi];
                }
            }
        }
    }
}

// x (B,C,T) f32 -> xt (B,T,C) bf16, 32x32 LDS tiles
__global__ __launch_bounds__(256)
void transpose_cast_x(const float* __restrict__ x, bf16* __restrict__ xt)
{
    __shared__ float tile[32][33];
    int b = blockIdx.z;
    int c0 = blockIdx.y * 32, t0 = blockIdx.x * 32;
    int tx = threadIdx.x & 31, ty = threadIdx.x >> 5;  // ty 0..7
    const float* xb = x + (long)b * 1024 * 1024;
    #pragma unroll
    for (int i = 0; i < 4; ++i) {
        int c = ty + i * 8;
        tile[c][tx] = xb[(long)(c0 + c) * 1024 + t0 + tx];
    }
    __syncthreads();
    bf16* xtb = xt + (long)b * 1024 * 1024;
    #pragma unroll
    for (int i = 0; i < 4; ++i) {
        int t = ty + i * 8;
        xtb[(long)(t0 + t) * 1024 + c0 + tx] = __float2bfloat16(tile[tx][t]);
    }
}

__global__ __launch_bounds__(256)
void cast_f2b(const float* __restrict__ in, bf16* __restrict__ out, long n)
{
    long i = (long)blockIdx.x * 256 + threadIdx.x;
    long stride = (long)gridDim.x * 256;
    for (; i < n; i += stride) out[i] = __float2bfloat16(in[i]);
}

// Build stacked qk weight (2048 x 1024 bf16)
__global__ __launch_bounds__(256)
void build_wqk(const float* __restrict__ Wq, const float* __restrict__ Wk,
               const float* __restrict__ bq, const float* __restrict__ bk,
               bf16* __restrict__ Wqk, float* __restrict__ biasqk)
{
    long i = (long)blockIdx.x * 256 + threadIdx.x;   // 2048*1024 total
    long r = i >> 10, c = i & 1023;
    long h = r >> 8, rr = r & 255;
    float v = (rr < 128) ? Wq[(h * 128 + rr) * 1024 + c]
                         : Wk[(h * 128 + (rr - 128)) * 1024 + c];
    Wqk[i] = __float2bfloat16(v);
    if (c == 0)
        biasqk[r] = (rr < 128) ? bq[h * 128 + rr] : bk[h * 128 + rr - 128];
}

// one block per row: softmax over 1024 fp32 logits -> bf16 IN PLACE (upper half of the f32 row)
__global__ __launch_bounds__(256)
void softmax_rows(const float* __restrict__ E, bf16* __restrict__ A)
{
    long row = blockIdx.x;
    const float* e = E + row * 1024;
    bf16* a = A + row * 2048;              // A pre-offset by +1024 bf16 elements
    int tid = threadIdx.x;
    int wave = tid >> 6, lane = tid & 63;
    float v[4];
    float mx = -1e30f;
    #pragma unroll
    for (int i = 0; i < 4; ++i) { v[i] = e[tid + i * 256]; mx = fmaxf(mx, v[i]); }
    #pragma unroll
    for (int off = 32; off; off >>= 1) mx = fmaxf(mx, __shfl_xor(mx, off, 64));
    __shared__ float red[4], red2[4];
    if (lane == 0) red[wave] = mx;
    __syncthreads();
    mx = fmaxf(fmaxf(red[0], red[1]), fmaxf(red[2], red[3]));
    float s = 0.f;
    #pragma unroll
    for (int i = 0; i < 4; ++i) { v[i] = __expf(v[i] - mx); s += v[i]; }
    #pragma unroll
    for (int off = 32; off; off >>= 1) s += __shfl_xor(s, off, 64);
    if (lane == 0) red2[wave] = s;
    __syncthreads();
    s = red2[0] + red2[1] + red2[2] + red2[3];
    float inv = 1.0f / s;
    #pragma unroll
    for (int i = 0; i < 4; ++i) a[tid + i * 256] = __float2bfloat16(v[i] * inv);
}

extern "C" void kernel_launch(void* const* d_in, const int* in_sizes, int n_in,
                              void* d_out, int out_size, void* d_ws, size_t ws_size,
                              hipStream_t stream)
{
    const float* x     = (const float*)d_in[0];
    const float* Wq    = (const float*)d_in[1];
    const float* bq    = (const float*)d_in[2];
    const float* Wk    = (const float*)d_in[3];
    const float* bk    = (const float*)d_in[4];
    const float* Wv    = (const float*)d_in[5];
    const float* bv    = (const float*)d_in[6];
    const float* gamma = (const float*)d_in[7];
    const float* W1    = (const float*)d_in[8];
    const float* b1    = (const float*)d_in[9];
    const float* W2    = (const float*)d_in[10];
    const float* b2    = (const float*)d_in[11];
    float* out = (float*)d_out;

    // chunk = batches processed per attention pass. chunk=2 needs ~214 MiB.
    const int chunk = (ws_size >= (230ll << 20)) ? 2 : 1;
    const int nq = 8 / chunk;

    char* p = (char*)d_ws;
    auto alloc = [&](size_t bytes) { char* r = p; p += (bytes + 255) & ~(size_t)255; return r; };
    bf16*  xt   = (bf16*)alloc(8ll * 1024 * 1024 * 2);          // (B,T,C)      16 MiB
    bf16*  Wqk  = (bf16*)alloc(2048ll * 1024 * 2);              //               4 MiB
    bf16*  Wvb  = (bf16*)alloc(8192ll * 1024 * 2);              // (H*C, C)     16 MiB
    bf16*  W1b  = (bf16*)alloc(128ll * 1024 * 2);
    bf16*  W2b  = (bf16*)alloc(128ll * 128 * 2);
    float* bqk  = (float*)alloc(2048 * 4);
    bf16*  qkt  = (bf16*)alloc(8192ll * 2048 * 2);              // (b*T+t, 2048) 32 MiB
    bf16*  y1   = (bf16*)alloc(65536ll * 128 * 2);              //               16 MiB
    bf16*  vbuf = (bf16*)alloc((long)chunk * 8 * 1024 * 1024 * 2);   // chunk=2: 32 MiB
    float* Ebuf = (float*)alloc((long)chunk * 8 * 1024 * 1024 * 4);  // chunk=2: 64 MiB
    bf16*  ot   = (bf16*)alloc((long)chunk * 8 * 1024 * 1024 * 2);   // chunk=2: 32 MiB

    dim3 blk(256);
    transpose_cast_x<<<dim3(32, 32, 8), blk, 0, stream>>>(x, xt);
    build_wqk<<<8192, blk, 0, stream>>>(Wq, Wk, bq, bk, Wqk, bqk);
    cast_f2b<<<4096, blk, 0, stream>>>(Wv, Wvb, 8192ll * 1024);
    cast_f2b<<<512, blk, 0, stream>>>(W1, W1b, 128 * 1024);
    cast_f2b<<<64, blk, 0, stream>>>(W2, W2b, 128 * 128);

    const long M1 = 1048576, M2 = 2097152, M8 = 8388608, M16 = 16777216;

    // qk_t: M=8192 (b,t), N=2048 (h*256+o), K=1024 — full batch
    gemm_nt<1, 64><<<dim3(16, 64, 1), blk, 0, stream>>>(
        xt, 1024, 0, 0, Wqk, 1024, 0, 0, qkt, 2048, 0, 0, 1024,
        bqk, 0, nullptr, nullptr, 0, nullptr);

    for (int q = 0; q < nq; ++q) {
        const long b0 = (long)q * chunk;
        const bf16* xtq = xt + b0 * M1;
        // v(zb,zh;c,s) = Wv[zh](c,ci) . xt(b0+zb;s,ci)^T + bv[zh,c]
        gemm_nt<0, 64><<<dim3(8, 8, 8 * chunk), blk, 0, stream>>>(
            Wvb, 1024, 0, M1, xtq, 1024, M1, 0, vbuf, 1024, M8, M1, 1024,
            bv, 1024, nullptr, nullptr, 0, nullptr);
        // E(zb,zh;t,s) = q.k^T, K=128, single-stage
        gemm_nt<2, 128><<<dim3(8, 8, 8 * chunk), blk, 0, stream>>>(
            qkt + b0 * M2, 2048, M2, 256, qkt + b0 * M2 + 128, 2048, M2, 256,
            Ebuf, 1024, M8, M1, 128,
            nullptr, 0, nullptr, nullptr, 0, nullptr);
        softmax_rows<<<8192 * chunk, blk, 0, stream>>>(Ebuf, (bf16*)Ebuf + 1024);
        // heads_t(zb,zh;t,c) = gamma[zh]*(attn(t,s).v(c,s)^T) + xt(b0+zb;t,c)
        gemm_nt<3, 64><<<dim3(8, 8, 8 * chunk), blk, 0, stream>>>(
            (bf16*)Ebuf + 1024, 2048, M16, M2, vbuf, 1024, M8, M1,
            ot, 1024, M8, M1, 1024,
            nullptr, 0, gamma, xtq, 1024, nullptr);
        // y1 slice = relu(ot . W1^T + b1): M=8192*chunk, N=128, K=1024
        gemm_nt<4, 64><<<dim3(1, 64 * chunk, 1), blk, 0, stream>>>(
            ot, 1024, 0, 0, W1b, 1024, 0, 0, y1 + b0 * 8192 * 128, 128, 0, 0, 1024,
            b1, 0, nullptr, nullptr, 0, nullptr);
    }

    // out = relu(y1 . W2^T + b2) scattered + x: M=65536, N=128, K=128 — full batch
    gemm_nt<5, 128><<<dim3(1, 512, 1), blk, 0, stream>>>(
        y1, 128, 0, 0, W2b, 128, 0, 0, out, 0, 0, 0, 128,
        b2, 0, nullptr, nullptr, 0, x);
}

// Round 6
// 765.198 us; speedup vs baseline: 1.5631x; 1.1327x over previous
//
#include <hip/hip_runtime.h>
#include <hip/hip_bf16.h>

typedef __hip_bfloat16 bf16;
typedef __attribute__((ext_vector_type(8))) __bf16 bf16x8;
typedef __attribute__((ext_vector_type(4))) float f32x4;

#define BM 128
#define BN 128

typedef const __attribute__((address_space(1))) void gvoid;
typedef __attribute__((address_space(3))) void lvoid;

// NT GEMM: C[m,n] = sum_k A[m,k] * B[n,k]   (both row-major, K contiguous)
// z decomposes as zb = z>>3 (local batch), zh = z&7 (head).
// SLICEX: slice index lives in blockIdx.x (XCD-pinned), n-tile in blockIdx.z.
// MODE 0: C bf16 = acc + bias[zh*sBiasZ + m]                 (v proj)
// MODE 1: C bf16 = acc + bias[n]                             (qk proj)
// MODE 3: C bf16 = gamma[zh]*acc + xt[zb*1M + m*ldxt + n]    (o -> heads_t)
// MODE 4: C bf16 = relu(acc + bias[n])                       (fc1)
// MODE 5: out f32 scatter + residual (m is GLOBAL row b*8192+h*1024+t)
template<int MODE, int TBK, bool SLICEX>
__global__ __launch_bounds__(256)
void gemm_nt(const bf16* __restrict__ A, long lda, long sAb, long sAh,
             const bf16* __restrict__ B, long ldb, long sBb, long sBh,
             void* __restrict__ Cv, long ldc, long sCb, long sCh,
             int K,
             const float* __restrict__ bias, long sBiasZ,
             const float* __restrict__ gamma,
             const bf16* __restrict__ xt, long ldxt,
             const float* __restrict__ xf)
{
    __shared__ bf16 As[BM * TBK];
    __shared__ bf16 Bs[BN * TBK];
    const int bxt = SLICEX ? blockIdx.z : blockIdx.x;   // n-tile
    const int z   = SLICEX ? blockIdx.x : blockIdx.z;   // slice
    const int zb = z >> 3, zh = z & 7;
    const bf16* Ab = A + (long)zb * sAb + (long)zh * sAh + (long)blockIdx.y * BM * lda;
    const bf16* Bb = B + (long)zb * sBb + (long)zh * sBh + (long)bxt * BN * ldb;
    const int tid  = threadIdx.x;
    const int wave = tid >> 6, lane = tid & 63;
    const int col  = lane & 15, quad = lane >> 4;
    const int wm = (wave & 1) * 64, wn = (wave >> 1) * 64;
    constexpr int CPR = TBK / 8;            // 16B chunks per row

    f32x4 acc[4][4] = {};

    for (int k0 = 0; k0 < K; k0 += TBK) {
        __syncthreads();
        #pragma unroll
        for (int i = 0; i < TBK / 16; ++i) {
            int cbase = i * 256 + wave * 64;     // wave-uniform chunk base
            int c = cbase + lane;                // chunk id
            int m = c / CPR;                     // tile row
            int j = c % CPR;                     // chunk slot in row
            int kch = ((j ^ (m & 7)) << 3);      // swizzled k offset (elements)
            __builtin_amdgcn_global_load_lds(
                (gvoid*)(Ab + (long)m * lda + k0 + kch),
                (lvoid*)(As + cbase * 8), 16, 0, 0);
            __builtin_amdgcn_global_load_lds(
                (gvoid*)(Bb + (long)m * ldb + k0 + kch),
                (lvoid*)(Bs + cbase * 8), 16, 0, 0);
        }
        __syncthreads();
        #pragma unroll
        for (int kk = 0; kk < TBK; kk += 32) {
            bf16x8 af[4], bfr[4];
            int kq = (kk >> 3) + quad;
            #pragma unroll
            for (int mi = 0; mi < 4; ++mi) {
                int m = wm + mi * 16 + col;
                af[mi] = *(const bf16x8*)(As + m * TBK + ((kq ^ (m & 7)) << 3));
            }
            #pragma unroll
            for (int ni = 0; ni < 4; ++ni) {
                int n = wn + ni * 16 + col;
                bfr[ni] = *(const bf16x8*)(Bs + n * TBK + ((kq ^ (n & 7)) << 3));
            }
            #pragma unroll
            for (int mi = 0; mi < 4; ++mi)
                #pragma unroll
                for (int ni = 0; ni < 4; ++ni)
                    acc[mi][ni] = __builtin_amdgcn_mfma_f32_16x16x32_bf16(
                        af[mi], bfr[ni], acc[mi][ni], 0, 0, 0);
        }
    }

    const long m0 = (long)blockIdx.y * BM + wm;
    const long n0 = (long)bxt * BN + wn;
    float g = 0.f;
    if (MODE == 3) g = gamma[zh];
    #pragma unroll
    for (int mi = 0; mi < 4; ++mi) {
        #pragma unroll
        for (int ni = 0; ni < 4; ++ni) {
            long mb = m0 + mi * 16 + quad * 4;
            long n  = n0 + ni * 16 + col;
            #pragma unroll
            for (int r = 0; r < 4; ++r) {
                long m = mb + r;
                float v = acc[mi][ni][r];
                if constexpr (MODE == 0) {
                    v += bias[zh * sBiasZ + m];
                    ((bf16*)Cv)[(long)zb * sCb + (long)zh * sCh + m * ldc + n] = __float2bfloat16(v);
                } else if constexpr (MODE == 1) {
                    v += bias[n];
                    ((bf16*)Cv)[m * ldc + n] = __float2bfloat16(v);
                } else if constexpr (MODE == 3) {
                    float xv = __bfloat162float(xt[(long)zb * 1048576 + m * ldxt + n]);
                    ((bf16*)Cv)[(long)zb * sCb + (long)zh * sCh + m * ldc + n] = __float2bfloat16(g * v + xv);
                } else if constexpr (MODE == 4) {
                    v += bias[n];
                    v = v > 0.f ? v : 0.f;
                    ((bf16*)Cv)[m * ldc + n] = __float2bfloat16(v);
                } else {  // MODE 5: m global = b*8192 + h*1024 + t
                    v += bias[n];
                    v = v > 0.f ? v : 0.f;
                    long bb = m >> 13, h = (m >> 10) & 7, t = m & 1023;
                    long oi = bb * 1048576 + (n * 8 + h) * 1024 + t;
                    ((float*)Cv)[oi] = v + xf[oi];
                }
            }
        }
    }
}

// Fused energy + softmax. Grid: (slices, T/32). Block 256 (4 waves).
// Per block: Q-tile 32x128 in LDS->regs, S(32,1024) in registers (wave w owns
// cols {si*128 + w*32 + [0,32)}), row softmax via intra-quad shfl + LDS combine,
// P -> bf16 via a 16-row LDS bounce done twice (mi=0 rows 0-15, mi=1 rows 16-31).
// R4/R5 BUG (fixed): copy phase used rowh=c>>6, jj=c&63 -> only 64 chunks = 512
// of 1024 cols per row copied; right half of attb stayed poisoned. Correct:
// 128 chunks/row -> rowh=c>>7, jj=c&127, 8 iters x 256 threads = 2048 chunks.
__global__ __launch_bounds__(256, 2)
void attn_fused(const bf16* __restrict__ qk, bf16* __restrict__ attn)
{
    constexpr int PAD = 1032;
    __shared__ __align__(16) char smraw[40960];   // phase A: Q 8K + K 32K; phase B: Sbuf 33024B
    __shared__ float red[2][4][32];
    bf16* Qs = (bf16*)smraw;                  // [32][128]
    bf16* Ks = (bf16*)(smraw + 8192);         // [128][128]
    bf16* Sbuf = (bf16*)smraw;                // [16][PAD]

    const int z = blockIdx.x;
    const int zb = z >> 3, zh = z & 7;
    const int t0 = blockIdx.y * 32;
    const int tid = threadIdx.x, w = tid >> 6, lane = tid & 63;
    const int col = lane & 15, quad = lane >> 4;

    const bf16* Qbase = qk + ((long)zb * 1024 + t0) * 2048 + zh * 256;
    const bf16* Kbase = qk + (long)zb * 1024 * 2048 + zh * 256 + 128;

    // stage Q tile (32x128): 512 chunks of 16B
    #pragma unroll
    for (int i = 0; i < 2; ++i) {
        int cbase = i * 256 + w * 64;
        int c = cbase + lane;
        int m = c >> 4, j = c & 15;
        __builtin_amdgcn_global_load_lds(
            (gvoid*)(Qbase + (long)m * 2048 + ((j ^ (m & 7)) << 3)),
            (lvoid*)(Qs + cbase * 8), 16, 0, 0);
    }
    __syncthreads();
    bf16x8 af[2][4];
    #pragma unroll
    for (int mi = 0; mi < 2; ++mi) {
        int m = mi * 16 + col;
        #pragma unroll
        for (int ki = 0; ki < 4; ++ki)
            af[mi][ki] = *(const bf16x8*)(Qs + m * 128 + ((((ki << 2) + quad) ^ (m & 7)) << 3));
    }

    f32x4 acc[2][16] = {};
    #pragma unroll
    for (int si = 0; si < 8; ++si) {
        __syncthreads();
        const bf16* Kb = Kbase + (long)si * 128 * 2048;
        #pragma unroll
        for (int i = 0; i < 8; ++i) {
            int cbase = i * 256 + w * 64;
            int c = cbase + lane;
            int m = c >> 4, j = c & 15;
            __builtin_amdgcn_global_load_lds(
                (gvoid*)(Kb + (long)m * 2048 + ((j ^ (m & 7)) << 3)),
                (lvoid*)(Ks + cbase * 8), 16, 0, 0);
        }
        __syncthreads();
        bf16x8 bfr[2][4];
        #pragma unroll
        for (int ni = 0; ni < 2; ++ni) {
            int n = w * 32 + ni * 16 + col;
            #pragma unroll
            for (int ki = 0; ki < 4; ++ki)
                bfr[ni][ki] = *(const bf16x8*)(Ks + n * 128 + ((((ki << 2) + quad) ^ (n & 7)) << 3));
        }
        #pragma unroll
        for (int ki = 0; ki < 4; ++ki)
            #pragma unroll
            for (int mi = 0; mi < 2; ++mi)
                #pragma unroll
                for (int ni = 0; ni < 2; ++ni)
                    acc[mi][si * 2 + ni] = __builtin_amdgcn_mfma_f32_16x16x32_bf16(
                        af[mi][ki], bfr[ni][ki], acc[mi][si * 2 + ni], 0, 0, 0);
    }

    // row max (rows: mi*16 + quad*4 + r; this wave's cols: {si*128 + w*32 + [0,32)})
    float rmx[2][4], rinv[2][4];
    #pragma unroll
    for (int mi = 0; mi < 2; ++mi)
        #pragma unroll
        for (int r = 0; r < 4; ++r) {
            float mx = acc[mi][0][r];
            #pragma unroll
            for (int j = 1; j < 16; ++j) mx = fmaxf(mx, acc[mi][j][r]);
            #pragma unroll
            for (int off = 1; off < 16; off <<= 1) mx = fmaxf(mx, __shfl_xor(mx, off, 64));
            rmx[mi][r] = mx;
        }
    if (col == 0) {
        #pragma unroll
        for (int mi = 0; mi < 2; ++mi)
            #pragma unroll
            for (int r = 0; r < 4; ++r)
                red[0][w][mi * 16 + quad * 4 + r] = rmx[mi][r];
    }
    __syncthreads();
    #pragma unroll
    for (int mi = 0; mi < 2; ++mi)
        #pragma unroll
        for (int r = 0; r < 4; ++r) {
            int row = mi * 16 + quad * 4 + r;
            rmx[mi][r] = fmaxf(fmaxf(red[0][0][row], red[0][1][row]),
                               fmaxf(red[0][2][row], red[0][3][row]));
        }
    // exp + row sum
    #pragma unroll
    for (int mi = 0; mi < 2; ++mi)
        #pragma unroll
        for (int r = 0; r < 4; ++r) {
            float s = 0.f;
            #pragma unroll
            for (int j = 0; j < 16; ++j) {
                acc[mi][j][r] = __expf(acc[mi][j][r] - rmx[mi][r]);
                s += acc[mi][j][r];
            }
            #pragma unroll
            for (int off = 1; off < 16; off <<= 1) s += __shfl_xor(s, off, 64);
            rinv[mi][r] = s;
        }
    if (col == 0) {
        #pragma unroll
        for (int mi = 0; mi < 2; ++mi)
            #pragma unroll
            for (int r = 0; r < 4; ++r)
                red[1][w][mi * 16 + quad * 4 + r] = rinv[mi][r];
    }
    __syncthreads();
    #pragma unroll
    for (int mi = 0; mi < 2; ++mi)
        #pragma unroll
        for (int r = 0; r < 4; ++r) {
            int row = mi * 16 + quad * 4 + r;
            float s4 = red[1][0][row] + red[1][1][row] + red[1][2][row] + red[1][3][row];
            rinv[mi][r] = 1.0f / s4;
        }

    // two-phase writeout: 16 rows at a time through Sbuf (overlays Qs/Ks; all
    // LDS reads of phase A are >=2 barriers behind)
    bf16* dst = attn + ((long)(zb * 8 + zh)) * 1048576 + (long)t0 * 1024;
    #pragma unroll
    for (int mi = 0; mi < 2; ++mi) {
        __syncthreads();           // Sbuf free (phase A done / previous half copied)
        #pragma unroll
        for (int j = 0; j < 16; ++j) {
            int colb = (j >> 1) * 128 + w * 32 + (j & 1) * 16 + col;
            #pragma unroll
            for (int r = 0; r < 4; ++r) {
                int rowh = quad * 4 + r;       // row within this 16-row half
                Sbuf[rowh * PAD + colb] = __float2bfloat16(acc[mi][j][r] * rinv[mi][r]);
            }
        }
        __syncthreads();
        #pragma unroll
        for (int i = 0; i < 8; ++i) {
            int c = i * 256 + tid;             // 0..2047 chunks (16 rows x 128 chunks)
            int rowh = c >> 7, jj = c & 127;
            bf16x8 vv = *(const bf16x8*)(Sbuf + rowh * PAD + jj * 8);
            *(bf16x8*)(dst + (long)(mi * 16 + rowh) * 1024 + jj * 8) = vv;
        }
    }
}

// x (B,C,T) f32 -> xt (B,T,C) bf16, 32x32 LDS tiles
__global__ __launch_bounds__(256)
void transpose_cast_x(const float* __restrict__ x, bf16* __restrict__ xt)
{
    __shared__ float tile[32][33];
    int b = blockIdx.z;
    int c0 = blockIdx.y * 32, t0 = blockIdx.x * 32;
    int tx = threadIdx.x & 31, ty = threadIdx.x >> 5;  // ty 0..7
    const float* xb = x + (long)b * 1024 * 1024;
    #pragma unroll
    for (int i = 0; i < 4; ++i) {
        int c = ty + i * 8;
        tile[c][tx] = xb[(long)(c0 + c) * 1024 + t0 + tx];
    }
    __syncthreads();
    bf16* xtb = xt + (long)b * 1024 * 1024;
    #pragma unroll
    for (int i = 0; i < 4; ++i) {
        int t = ty + i * 8;
        xtb[(long)(t0 + t) * 1024 + c0 + tx] = __float2bfloat16(tile[tx][t]);
    }
}

__global__ __launch_bounds__(256)
void cast_f2b(const float* __restrict__ in, bf16* __restrict__ out, long n)
{
    long i = (long)blockIdx.x * 256 + threadIdx.x;
    long stride = (long)gridDim.x * 256;
    for (; i < n; i += stride) out[i] = __float2bfloat16(in[i]);
}

// Build stacked qk weight (2048 x 1024 bf16)
__global__ __launch_bounds__(256)
void build_wqk(const float* __restrict__ Wq, const float* __restrict__ Wk,
               const float* __restrict__ bq, const float* __restrict__ bk,
               bf16* __restrict__ Wqk, float* __restrict__ biasqk)
{
    long i = (long)blockIdx.x * 256 + threadIdx.x;   // 2048*1024 total
    long r = i >> 10, c = i & 1023;
    long h = r >> 8, rr = r & 255;
    float v = (rr < 128) ? Wq[(h * 128 + rr) * 1024 + c]
                         : Wk[(h * 128 + (rr - 128)) * 1024 + c];
    Wqk[i] = __float2bfloat16(v);
    if (c == 0)
        biasqk[r] = (rr < 128) ? bq[h * 128 + rr] : bk[h * 128 + rr - 128];
}

extern "C" void kernel_launch(void* const* d_in, const int* in_sizes, int n_in,
                              void* d_out, int out_size, void* d_ws, size_t ws_size,
                              hipStream_t stream)
{
    const float* x     = (const float*)d_in[0];
    const float* Wq    = (const float*)d_in[1];
    const float* bq    = (const float*)d_in[2];
    const float* Wk    = (const float*)d_in[3];
    const float* bk    = (const float*)d_in[4];
    const float* Wv    = (const float*)d_in[5];
    const float* bv    = (const float*)d_in[6];
    const float* gamma = (const float*)d_in[7];
    const float* W1    = (const float*)d_in[8];
    const float* b1    = (const float*)d_in[9];
    const float* W2    = (const float*)d_in[10];
    const float* b2    = (const float*)d_in[11];
    float* out = (float*)d_out;

    const int chunk = 2;            // attention batches per pass (~180 MiB total ws)
    const int nq = 8 / chunk;

    char* p = (char*)d_ws;
    auto alloc = [&](size_t bytes) { char* r = p; p += (bytes + 255) & ~(size_t)255; return r; };
    bf16*  xt   = (bf16*)alloc(8ll * 1024 * 1024 * 2);          // (B,T,C)      16 MiB
    bf16*  Wqk  = (bf16*)alloc(2048ll * 1024 * 2);              //               4 MiB
    bf16*  Wvb  = (bf16*)alloc(8192ll * 1024 * 2);              // (H*C, C)     16 MiB
    bf16*  W1b  = (bf16*)alloc(128ll * 1024 * 2);
    bf16*  W2b  = (bf16*)alloc(128ll * 128 * 2);
    float* bqk  = (float*)alloc(2048 * 4);
    bf16*  qkt  = (bf16*)alloc(8192ll * 2048 * 2);              // (b*T+t, 2048) 32 MiB
    bf16*  y1   = (bf16*)alloc(65536ll * 128 * 2);              //               16 MiB
    bf16*  vbuf = (bf16*)alloc((long)chunk * 8 * 1024 * 1024 * 2);   // 32 MiB
    bf16*  attb = (bf16*)alloc((long)chunk * 8 * 1024 * 1024 * 2);   // 32 MiB
    bf16*  ot   = (bf16*)alloc((long)chunk * 8 * 1024 * 1024 * 2);   // 32 MiB

    dim3 blk(256);
    transpose_cast_x<<<dim3(32, 32, 8), blk, 0, stream>>>(x, xt);
    build_wqk<<<8192, blk, 0, stream>>>(Wq, Wk, bq, bk, Wqk, bqk);
    cast_f2b<<<4096, blk, 0, stream>>>(Wv, Wvb, 8192ll * 1024);
    cast_f2b<<<512, blk, 0, stream>>>(W1, W1b, 128 * 1024);
    cast_f2b<<<64, blk, 0, stream>>>(W2, W2b, 128 * 128);

    const long M1 = 1048576, M2 = 2097152, M8 = 8388608;

    // qk_t: M=8192 (b,t), N=2048 (h*256+o), K=1024 — full batch
    gemm_nt<1, 64, false><<<dim3(16, 64, 1), blk, 0, stream>>>(
        xt, 1024, 0, 0, Wqk, 1024, 0, 0, qkt, 2048, 0, 0, 1024,
        bqk, 0, nullptr, nullptr, 0, nullptr);

    for (int q = 0; q < nq; ++q) {
        const long b0 = (long)q * chunk;
        const bf16* xtq = xt + b0 * M1;
        // v(zb,zh;c,s) = Wv[zh](c,ci) . xt(b0+zb;s,ci)^T + bv[zh,c]  [slice in grid.x]
        gemm_nt<0, 64, true><<<dim3(8 * chunk, 8, 8), blk, 0, stream>>>(
            Wvb, 1024, 0, M1, xtq, 1024, M1, 0, vbuf, 1024, M8, M1, 1024,
            bv, 1024, nullptr, nullptr, 0, nullptr);
        // fused E + softmax -> attb bf16
        attn_fused<<<dim3(8 * chunk, 32, 1), blk, 0, stream>>>(
            qkt + b0 * M2, attb);
        // heads_t(zb,zh;t,c) = gamma[zh]*(attn(t,s).v(c,s)^T) + xt(b0+zb;t,c)
        gemm_nt<3, 64, true><<<dim3(8 * chunk, 8, 8), blk, 0, stream>>>(
            attb, 1024, M8, M1, vbuf, 1024, M8, M1,
            ot, 1024, M8, M1, 1024,
            nullptr, 0, gamma, xtq, 1024, nullptr);
        // y1 slice = relu(ot . W1^T + b1): M=8192*chunk, N=128, K=1024
        gemm_nt<4, 64, false><<<dim3(1, 64 * chunk, 1), blk, 0, stream>>>(
            ot, 1024, 0, 0, W1b, 1024, 0, 0, y1 + b0 * 8192 * 128, 128, 0, 0, 1024,
            b1, 0, nullptr, nullptr, 0, nullptr);
    }

    // out = relu(y1 . W2^T + b2) scattered + x: M=65536, N=128, K=128 — full batch
    gemm_nt<5, 128, false><<<dim3(1, 512, 1), blk, 0, stream>>>(
        y1, 128, 0, 0, W2b, 128, 0, 0, out, 0, 0, 0, 128,
        b2, 0, nullptr, nullptr, 0, x);
}

// Round 7
// 712.248 us; speedup vs baseline: 1.6793x; 1.0743x over previous
//
#include <hip/hip_runtime.h>
#include <hip/hip_bf16.h>

typedef __hip_bfloat16 bf16;
typedef __attribute__((ext_vector_type(8))) __bf16 bf16x8;
typedef __attribute__((ext_vector_type(4))) float f32x4;

#define BM 128
#define BN 128

typedef const __attribute__((address_space(1))) void gvoid;
typedef __attribute__((address_space(3))) void lvoid;

// NT GEMM: C[m,n] = sum_k A[m,k] * B[n,k]   (both row-major, K contiguous)
// z decomposes as zb = z>>3 (local batch), zh = z&7 (head).
// SLICEX: slice index lives in blockIdx.x (XCD-pinned), n-tile in blockIdx.z.
// MODE 0: C bf16 = acc + bias[zh*sBiasZ + m]                 (v proj)
// MODE 1: C bf16 = acc + bias[n]                             (qk proj)
// MODE 3: C bf16 = gamma[zh]*acc + xt[zb*1M + m*ldxt + n]    (o -> heads_t)
// MODE 4: C bf16 = relu(acc + bias[n])                       (fc1)
// MODE 5: out f32 scatter + residual (m is GLOBAL row b*8192+h*1024+t)
template<int MODE, int TBK, bool SLICEX>
__global__ __launch_bounds__(256)
void gemm_nt(const bf16* __restrict__ A, long lda, long sAb, long sAh,
             const bf16* __restrict__ B, long ldb, long sBb, long sBh,
             void* __restrict__ Cv, long ldc, long sCb, long sCh,
             int K,
             const float* __restrict__ bias, long sBiasZ,
             const float* __restrict__ gamma,
             const bf16* __restrict__ xt, long ldxt,
             const float* __restrict__ xf)
{
    __shared__ bf16 As[BM * TBK];
    __shared__ bf16 Bs[BN * TBK];
    const int bxt = SLICEX ? blockIdx.z : blockIdx.x;   // n-tile
    const int z   = SLICEX ? blockIdx.x : blockIdx.z;   // slice
    const int zb = z >> 3, zh = z & 7;
    const bf16* Ab = A + (long)zb * sAb + (long)zh * sAh + (long)blockIdx.y * BM * lda;
    const bf16* Bb = B + (long)zb * sBb + (long)zh * sBh + (long)bxt * BN * ldb;
    const int tid  = threadIdx.x;
    const int wave = tid >> 6, lane = tid & 63;
    const int col  = lane & 15, quad = lane >> 4;
    const int wm = (wave & 1) * 64, wn = (wave >> 1) * 64;
    constexpr int CPR = TBK / 8;            // 16B chunks per row

    f32x4 acc[4][4] = {};

    for (int k0 = 0; k0 < K; k0 += TBK) {
        __syncthreads();
        #pragma unroll
        for (int i = 0; i < TBK / 16; ++i) {
            int cbase = i * 256 + wave * 64;     // wave-uniform chunk base
            int c = cbase + lane;                // chunk id
            int m = c / CPR;                     // tile row
            int j = c % CPR;                     // chunk slot in row
            int kch = ((j ^ (m & 7)) << 3);      // swizzled k offset (elements)
            __builtin_amdgcn_global_load_lds(
                (gvoid*)(Ab + (long)m * lda + k0 + kch),
                (lvoid*)(As + cbase * 8), 16, 0, 0);
            __builtin_amdgcn_global_load_lds(
                (gvoid*)(Bb + (long)m * ldb + k0 + kch),
                (lvoid*)(Bs + cbase * 8), 16, 0, 0);
        }
        __syncthreads();
        #pragma unroll
        for (int kk = 0; kk < TBK; kk += 32) {
            bf16x8 af[4], bfr[4];
            int kq = (kk >> 3) + quad;
            #pragma unroll
            for (int mi = 0; mi < 4; ++mi) {
                int m = wm + mi * 16 + col;
                af[mi] = *(const bf16x8*)(As + m * TBK + ((kq ^ (m & 7)) << 3));
            }
            #pragma unroll
            for (int ni = 0; ni < 4; ++ni) {
                int n = wn + ni * 16 + col;
                bfr[ni] = *(const bf16x8*)(Bs + n * TBK + ((kq ^ (n & 7)) << 3));
            }
            #pragma unroll
            for (int mi = 0; mi < 4; ++mi)
                #pragma unroll
                for (int ni = 0; ni < 4; ++ni)
                    acc[mi][ni] = __builtin_amdgcn_mfma_f32_16x16x32_bf16(
                        af[mi], bfr[ni], acc[mi][ni], 0, 0, 0);
        }
    }

    const long m0 = (long)blockIdx.y * BM + wm;
    const long n0 = (long)bxt * BN + wn;
    float g = 0.f;
    if (MODE == 3) g = gamma[zh];
    #pragma unroll
    for (int mi = 0; mi < 4; ++mi) {
        #pragma unroll
        for (int ni = 0; ni < 4; ++ni) {
            long mb = m0 + mi * 16 + quad * 4;
            long n  = n0 + ni * 16 + col;
            #pragma unroll
            for (int r = 0; r < 4; ++r) {
                long m = mb + r;
                float v = acc[mi][ni][r];
                if constexpr (MODE == 0) {
                    v += bias[zh * sBiasZ + m];
                    ((bf16*)Cv)[(long)zb * sCb + (long)zh * sCh + m * ldc + n] = __float2bfloat16(v);
                } else if constexpr (MODE == 1) {
                    v += bias[n];
                    ((bf16*)Cv)[m * ldc + n] = __float2bfloat16(v);
                } else if constexpr (MODE == 3) {
                    float xv = __bfloat162float(xt[(long)zb * 1048576 + m * ldxt + n]);
                    ((bf16*)Cv)[(long)zb * sCb + (long)zh * sCh + m * ldc + n] = __float2bfloat16(g * v + xv);
                } else if constexpr (MODE == 4) {
                    v += bias[n];
                    v = v > 0.f ? v : 0.f;
                    ((bf16*)Cv)[m * ldc + n] = __float2bfloat16(v);
                } else {  // MODE 5: m global = b*8192 + h*1024 + t
                    v += bias[n];
                    v = v > 0.f ? v : 0.f;
                    long bb = m >> 13, h = (m >> 10) & 7, t = m & 1023;
                    long oi = bb * 1048576 + (n * 8 + h) * 1024 + t;
                    ((float*)Cv)[oi] = v + xf[oi];
                }
            }
        }
    }
}

// Fused energy + softmax. Grid: (slices, T/32). Block 256 (4 waves).
// Per block: Q-tile 32x128 in LDS->regs, S(32,1024) in registers (wave w owns
// cols {si*128 + w*32 + [0,32)}), row softmax via intra-quad shfl + LDS combine,
// P -> bf16 via a 16-row LDS bounce done twice.
__global__ __launch_bounds__(256, 2)
void attn_fused(const bf16* __restrict__ qk, bf16* __restrict__ attn)
{
    constexpr int PAD = 1032;
    __shared__ __align__(16) char smraw[40960];   // phase A: Q 8K + K 32K; phase B: Sbuf 33024B
    __shared__ float red[2][4][32];
    bf16* Qs = (bf16*)smraw;                  // [32][128]
    bf16* Ks = (bf16*)(smraw + 8192);         // [128][128]
    bf16* Sbuf = (bf16*)smraw;                // [16][PAD]

    const int z = blockIdx.x;
    const int zb = z >> 3, zh = z & 7;
    const int t0 = blockIdx.y * 32;
    const int tid = threadIdx.x, w = tid >> 6, lane = tid & 63;
    const int col = lane & 15, quad = lane >> 4;

    const bf16* Qbase = qk + ((long)zb * 1024 + t0) * 2048 + zh * 256;
    const bf16* Kbase = qk + (long)zb * 1024 * 2048 + zh * 256 + 128;

    // stage Q tile (32x128): 512 chunks of 16B
    #pragma unroll
    for (int i = 0; i < 2; ++i) {
        int cbase = i * 256 + w * 64;
        int c = cbase + lane;
        int m = c >> 4, j = c & 15;
        __builtin_amdgcn_global_load_lds(
            (gvoid*)(Qbase + (long)m * 2048 + ((j ^ (m & 7)) << 3)),
            (lvoid*)(Qs + cbase * 8), 16, 0, 0);
    }
    __syncthreads();
    bf16x8 af[2][4];
    #pragma unroll
    for (int mi = 0; mi < 2; ++mi) {
        int m = mi * 16 + col;
        #pragma unroll
        for (int ki = 0; ki < 4; ++ki)
            af[mi][ki] = *(const bf16x8*)(Qs + m * 128 + ((((ki << 2) + quad) ^ (m & 7)) << 3));
    }

    f32x4 acc[2][16] = {};
    #pragma unroll
    for (int si = 0; si < 8; ++si) {
        __syncthreads();
        const bf16* Kb = Kbase + (long)si * 128 * 2048;
        #pragma unroll
        for (int i = 0; i < 8; ++i) {
            int cbase = i * 256 + w * 64;
            int c = cbase + lane;
            int m = c >> 4, j = c & 15;
            __builtin_amdgcn_global_load_lds(
                (gvoid*)(Kb + (long)m * 2048 + ((j ^ (m & 7)) << 3)),
                (lvoid*)(Ks + cbase * 8), 16, 0, 0);
        }
        __syncthreads();
        bf16x8 bfr[2][4];
        #pragma unroll
        for (int ni = 0; ni < 2; ++ni) {
            int n = w * 32 + ni * 16 + col;
            #pragma unroll
            for (int ki = 0; ki < 4; ++ki)
                bfr[ni][ki] = *(const bf16x8*)(Ks + n * 128 + ((((ki << 2) + quad) ^ (n & 7)) << 3));
        }
        #pragma unroll
        for (int ki = 0; ki < 4; ++ki)
            #pragma unroll
            for (int mi = 0; mi < 2; ++mi)
                #pragma unroll
                for (int ni = 0; ni < 2; ++ni)
                    acc[mi][si * 2 + ni] = __builtin_amdgcn_mfma_f32_16x16x32_bf16(
                        af[mi][ki], bfr[ni][ki], acc[mi][si * 2 + ni], 0, 0, 0);
    }

    // row max (rows: mi*16 + quad*4 + r; this wave's cols: {si*128 + w*32 + [0,32)})
    float rmx[2][4], rinv[2][4];
    #pragma unroll
    for (int mi = 0; mi < 2; ++mi)
        #pragma unroll
        for (int r = 0; r < 4; ++r) {
            float mx = acc[mi][0][r];
            #pragma unroll
            for (int j = 1; j < 16; ++j) mx = fmaxf(mx, acc[mi][j][r]);
            #pragma unroll
            for (int off = 1; off < 16; off <<= 1) mx = fmaxf(mx, __shfl_xor(mx, off, 64));
            rmx[mi][r] = mx;
        }
    if (col == 0) {
        #pragma unroll
        for (int mi = 0; mi < 2; ++mi)
            #pragma unroll
            for (int r = 0; r < 4; ++r)
                red[0][w][mi * 16 + quad * 4 + r] = rmx[mi][r];
    }
    __syncthreads();
    #pragma unroll
    for (int mi = 0; mi < 2; ++mi)
        #pragma unroll
        for (int r = 0; r < 4; ++r) {
            int row = mi * 16 + quad * 4 + r;
            rmx[mi][r] = fmaxf(fmaxf(red[0][0][row], red[0][1][row]),
                               fmaxf(red[0][2][row], red[0][3][row]));
        }
    // exp + row sum
    #pragma unroll
    for (int mi = 0; mi < 2; ++mi)
        #pragma unroll
        for (int r = 0; r < 4; ++r) {
            float s = 0.f;
            #pragma unroll
            for (int j = 0; j < 16; ++j) {
                acc[mi][j][r] = __expf(acc[mi][j][r] - rmx[mi][r]);
                s += acc[mi][j][r];
            }
            #pragma unroll
            for (int off = 1; off < 16; off <<= 1) s += __shfl_xor(s, off, 64);
            rinv[mi][r] = s;
        }
    if (col == 0) {
        #pragma unroll
        for (int mi = 0; mi < 2; ++mi)
            #pragma unroll
            for (int r = 0; r < 4; ++r)
                red[1][w][mi * 16 + quad * 4 + r] = rinv[mi][r];
    }
    __syncthreads();
    #pragma unroll
    for (int mi = 0; mi < 2; ++mi)
        #pragma unroll
        for (int r = 0; r < 4; ++r) {
            int row = mi * 16 + quad * 4 + r;
            float s4 = red[1][0][row] + red[1][1][row] + red[1][2][row] + red[1][3][row];
            rinv[mi][r] = 1.0f / s4;
        }

    // two-phase writeout: 16 rows at a time through Sbuf
    bf16* dst = attn + ((long)(zb * 8 + zh)) * 1048576 + (long)t0 * 1024;
    #pragma unroll
    for (int mi = 0; mi < 2; ++mi) {
        __syncthreads();
        #pragma unroll
        for (int j = 0; j < 16; ++j) {
            int colb = (j >> 1) * 128 + w * 32 + (j & 1) * 16 + col;
            #pragma unroll
            for (int r = 0; r < 4; ++r) {
                int rowh = quad * 4 + r;
                Sbuf[rowh * PAD + colb] = __float2bfloat16(acc[mi][j][r] * rinv[mi][r]);
            }
        }
        __syncthreads();
        #pragma unroll
        for (int i = 0; i < 8; ++i) {
            int c = i * 256 + tid;             // 16 rows x 128 chunks
            int rowh = c >> 7, jj = c & 127;
            bf16x8 vv = *(const bf16x8*)(Sbuf + rowh * PAD + jj * 8);
            *(bf16x8*)(dst + (long)(mi * 16 + rowh) * 1024 + jj * 8) = vv;
        }
    }
}

// x (B,C,T) f32 -> xt (B,T,C) bf16, 32x32 LDS tiles
__global__ __launch_bounds__(256)
void transpose_cast_x(const float* __restrict__ x, bf16* __restrict__ xt)
{
    __shared__ float tile[32][33];
    int b = blockIdx.z;
    int c0 = blockIdx.y * 32, t0 = blockIdx.x * 32;
    int tx = threadIdx.x & 31, ty = threadIdx.x >> 5;  // ty 0..7
    const float* xb = x + (long)b * 1024 * 1024;
    #pragma unroll
    for (int i = 0; i < 4; ++i) {
        int c = ty + i * 8;
        tile[c][tx] = xb[(long)(c0 + c) * 1024 + t0 + tx];
    }
    __syncthreads();
    bf16* xtb = xt + (long)b * 1024 * 1024;
    #pragma unroll
    for (int i = 0; i < 4; ++i) {
        int t = ty + i * 8;
        xtb[(long)(t0 + t) * 1024 + c0 + tx] = __float2bfloat16(tile[tx][t]);
    }
}

__global__ __launch_bounds__(256)
void cast_f2b(const float* __restrict__ in, bf16* __restrict__ out, long n)
{
    long i = (long)blockIdx.x * 256 + threadIdx.x;
    long stride = (long)gridDim.x * 256;
    for (; i < n; i += stride) out[i] = __float2bfloat16(in[i]);
}

// Build stacked qk weight (2048 x 1024 bf16)
__global__ __launch_bounds__(256)
void build_wqk(const float* __restrict__ Wq, const float* __restrict__ Wk,
               const float* __restrict__ bq, const float* __restrict__ bk,
               bf16* __restrict__ Wqk, float* __restrict__ biasqk)
{
    long i = (long)blockIdx.x * 256 + threadIdx.x;   // 2048*1024 total
    long r = i >> 10, c = i & 1023;
    long h = r >> 8, rr = r & 255;
    float v = (rr < 128) ? Wq[(h * 128 + rr) * 1024 + c]
                         : Wk[(h * 128 + (rr - 128)) * 1024 + c];
    Wqk[i] = __float2bfloat16(v);
    if (c == 0)
        biasqk[r] = (rr < 128) ? bq[h * 128 + rr] : bk[h * 128 + rr - 128];
}

extern "C" void kernel_launch(void* const* d_in, const int* in_sizes, int n_in,
                              void* d_out, int out_size, void* d_ws, size_t ws_size,
                              hipStream_t stream)
{
    const float* x     = (const float*)d_in[0];
    const float* Wq    = (const float*)d_in[1];
    const float* bq    = (const float*)d_in[2];
    const float* Wk    = (const float*)d_in[3];
    const float* bk    = (const float*)d_in[4];
    const float* Wv    = (const float*)d_in[5];
    const float* bv    = (const float*)d_in[6];
    const float* gamma = (const float*)d_in[7];
    const float* W1    = (const float*)d_in[8];
    const float* b1    = (const float*)d_in[9];
    const float* W2    = (const float*)d_in[10];
    const float* b2    = (const float*)d_in[11];
    float* out = (float*)d_out;

    const int chunk = 2;
    const int nq = 8 / chunk;

    // Workspace layout — exactly 256 MiB with overlays.
    // [0,16M)    xt
    // [16M,32M)  Wvb
    // [32M,160M) ot (full batch)   — OVERLAYS Wqk (32M..36M) + bqk (36M..),
    //                                both dead after qk-proj (before first O write)
    // [160M,192M) qkt              — after last attn_fused: y1 (160M..176M),
    //                                W1b (176M..176.25M), W2b next (cast late)
    // [192M,224M) vbuf (chunk)
    // [224M,256M) attb (chunk)
    char* base = (char*)d_ws;
    const long MB = 1048576;
    bf16*  xt   = (bf16*)(base);
    bf16*  Wvb  = (bf16*)(base + 16 * MB);
    bf16*  ot   = (bf16*)(base + 32 * MB);
    bf16*  Wqk  = (bf16*)(base + 32 * MB);          // dead after qk-proj
    float* bqk  = (float*)(base + 36 * MB);         // dead after qk-proj
    bf16*  qkt  = (bf16*)(base + 160 * MB);
    bf16*  y1   = (bf16*)(base + 160 * MB);         // after last attn_fused
    bf16*  W1b  = (bf16*)(base + 176 * MB);         // cast after last attn_fused
    bf16*  W2b  = (bf16*)(base + 176 * MB + 262144);
    bf16*  vbuf = (bf16*)(base + 192 * MB);
    bf16*  attb = (bf16*)(base + 224 * MB);

    dim3 blk(256);
    transpose_cast_x<<<dim3(32, 32, 8), blk, 0, stream>>>(x, xt);
    build_wqk<<<8192, blk, 0, stream>>>(Wq, Wk, bq, bk, Wqk, bqk);
    cast_f2b<<<4096, blk, 0, stream>>>(Wv, Wvb, 8192ll * 1024);

    const long M1 = 1048576, M2 = 2097152, M8 = 8388608;

    // qk_t: M=8192 (b,t), N=2048 (h*256+o), K=1024 — full batch
    gemm_nt<1, 64, false><<<dim3(16, 64, 1), blk, 0, stream>>>(
        xt, 1024, 0, 0, Wqk, 1024, 0, 0, qkt, 2048, 0, 0, 1024,
        bqk, 0, nullptr, nullptr, 0, nullptr);

    for (int q = 0; q < nq; ++q) {
        const long b0 = (long)q * chunk;
        const bf16* xtq = xt + b0 * M1;
        // v(zb,zh;c,s) = Wv[zh](c,ci) . xt(b0+zb;s,ci)^T + bv[zh,c]
        gemm_nt<0, 64, true><<<dim3(8 * chunk, 8, 8), blk, 0, stream>>>(
            Wvb, 1024, 0, M1, xtq, 1024, M1, 0, vbuf, 1024, M8, M1, 1024,
            bv, 1024, nullptr, nullptr, 0, nullptr);
        // fused E + softmax -> attb bf16
        attn_fused<<<dim3(8 * chunk, 32, 1), blk, 0, stream>>>(
            qkt + b0 * M2, attb);
        // heads_t(zb,zh;t,c) = gamma[zh]*(attn(t,s).v(c,s)^T) + xt(b0+zb;t,c)
        // writes ot rows for batches [b0, b0+chunk)
        gemm_nt<3, 64, true><<<dim3(8 * chunk, 8, 8), blk, 0, stream>>>(
            attb, 1024, M8, M1, vbuf, 1024, M8, M1,
            ot + b0 * M8, 1024, M8, M1, 1024,
            nullptr, 0, gamma, xtq, 1024, nullptr);
    }

    // qkt is dead now: cast FC weights into its region, then run FCs full-batch.
    cast_f2b<<<512, blk, 0, stream>>>(W1, W1b, 128 * 1024);
    cast_f2b<<<64, blk, 0, stream>>>(W2, W2b, 128 * 128);

    // y1 = relu(ot . W1^T + b1): M=65536, N=128, K=1024 — one dispatch, 512 blocks
    gemm_nt<4, 64, false><<<dim3(1, 512, 1), blk, 0, stream>>>(
        ot, 1024, 0, 0, W1b, 1024, 0, 0, y1, 128, 0, 0, 1024,
        b1, 0, nullptr, nullptr, 0, nullptr);
    // out = relu(y1 . W2^T + b2) scattered + x: M=65536, N=128, K=128
    gemm_nt<5, 128, false><<<dim3(1, 512, 1), blk, 0, stream>>>(
        y1, 128, 0, 0, W2b, 128, 0, 0, out, 0, 0, 0, 128,
        b2, 0, nullptr, nullptr, 0, x);
}

// Round 8
// 709.649 us; speedup vs baseline: 1.6854x; 1.0037x over previous
//
#include <hip/hip_runtime.h>
#include <hip/hip_bf16.h>

typedef __hip_bfloat16 bf16;
typedef __attribute__((ext_vector_type(8))) __bf16 bf16x8;
typedef __attribute__((ext_vector_type(4))) float f32x4;

#define BM 128
#define BN 128

typedef const __attribute__((address_space(1))) void gvoid;
typedef __attribute__((address_space(3))) void lvoid;

// NT GEMM: C[m,n] = sum_k A[m,k] * B[n,k]   (both row-major, K contiguous)
// z decomposes as zb = z>>3 (local batch), zh = z&7 (head).
// SLICEX: slice index lives in blockIdx.x (XCD-pinned: zh == XCD id), n-tile in blockIdx.z.
// MODE 0: C bf16 = acc + bias[zh*sBiasZ + m]                 (v proj)
// MODE 1: C bf16 = acc + bias[n]                             (qk proj)
// MODE 3: C bf16 = gamma[zh]*acc + xt[zb*1M + m*ldxt + n]    (o -> heads_t)
// MODE 4: C bf16 = relu(acc + bias[n])                       (fc1)
// MODE 5: out f32 scatter + residual (m local row; Cv/xf pre-offset per pass)
template<int MODE, int TBK, bool SLICEX>
__global__ __launch_bounds__(256)
void gemm_nt(const bf16* __restrict__ A, long lda, long sAb, long sAh,
             const bf16* __restrict__ B, long ldb, long sBb, long sBh,
             void* __restrict__ Cv, long ldc, long sCb, long sCh,
             int K,
             const float* __restrict__ bias, long sBiasZ,
             const float* __restrict__ gamma,
             const bf16* __restrict__ xt, long ldxt,
             const float* __restrict__ xf)
{
    __shared__ bf16 As[BM * TBK];
    __shared__ bf16 Bs[BN * TBK];
    const int bxt = SLICEX ? blockIdx.z : blockIdx.x;   // n-tile
    const int z   = SLICEX ? blockIdx.x : blockIdx.z;   // slice
    const int zb = z >> 3, zh = z & 7;
    const bf16* Ab = A + (long)zb * sAb + (long)zh * sAh + (long)blockIdx.y * BM * lda;
    const bf16* Bb = B + (long)zb * sBb + (long)zh * sBh + (long)bxt * BN * ldb;
    const int tid  = threadIdx.x;
    const int wave = tid >> 6, lane = tid & 63;
    const int col  = lane & 15, quad = lane >> 4;
    const int wm = (wave & 1) * 64, wn = (wave >> 1) * 64;
    constexpr int CPR = TBK / 8;            // 16B chunks per row

    f32x4 acc[4][4] = {};

    for (int k0 = 0; k0 < K; k0 += TBK) {
        __syncthreads();
        #pragma unroll
        for (int i = 0; i < TBK / 16; ++i) {
            int cbase = i * 256 + wave * 64;     // wave-uniform chunk base
            int c = cbase + lane;                // chunk id
            int m = c / CPR;                     // tile row
            int j = c % CPR;                     // chunk slot in row
            int kch = ((j ^ (m & 7)) << 3);      // swizzled k offset (elements)
            __builtin_amdgcn_global_load_lds(
                (gvoid*)(Ab + (long)m * lda + k0 + kch),
                (lvoid*)(As + cbase * 8), 16, 0, 0);
            __builtin_amdgcn_global_load_lds(
                (gvoid*)(Bb + (long)m * ldb + k0 + kch),
                (lvoid*)(Bs + cbase * 8), 16, 0, 0);
        }
        __syncthreads();
        #pragma unroll
        for (int kk = 0; kk < TBK; kk += 32) {
            bf16x8 af[4], bfr[4];
            int kq = (kk >> 3) + quad;
            #pragma unroll
            for (int mi = 0; mi < 4; ++mi) {
                int m = wm + mi * 16 + col;
                af[mi] = *(const bf16x8*)(As + m * TBK + ((kq ^ (m & 7)) << 3));
            }
            #pragma unroll
            for (int ni = 0; ni < 4; ++ni) {
                int n = wn + ni * 16 + col;
                bfr[ni] = *(const bf16x8*)(Bs + n * TBK + ((kq ^ (n & 7)) << 3));
            }
            #pragma unroll
            for (int mi = 0; mi < 4; ++mi)
                #pragma unroll
                for (int ni = 0; ni < 4; ++ni)
                    acc[mi][ni] = __builtin_amdgcn_mfma_f32_16x16x32_bf16(
                        af[mi], bfr[ni], acc[mi][ni], 0, 0, 0);
        }
    }

    const long m0 = (long)blockIdx.y * BM + wm;
    const long n0 = (long)bxt * BN + wn;
    float g = 0.f;
    if (MODE == 3) g = gamma[zh];
    #pragma unroll
    for (int mi = 0; mi < 4; ++mi) {
        #pragma unroll
        for (int ni = 0; ni < 4; ++ni) {
            long mb = m0 + mi * 16 + quad * 4;
            long n  = n0 + ni * 16 + col;
            #pragma unroll
            for (int r = 0; r < 4; ++r) {
                long m = mb + r;
                float v = acc[mi][ni][r];
                if constexpr (MODE == 0) {
                    v += bias[zh * sBiasZ + m];
                    ((bf16*)Cv)[(long)zb * sCb + (long)zh * sCh + m * ldc + n] = __float2bfloat16(v);
                } else if constexpr (MODE == 1) {
                    v += bias[n];
                    ((bf16*)Cv)[m * ldc + n] = __float2bfloat16(v);
                } else if constexpr (MODE == 3) {
                    float xv = __bfloat162float(xt[(long)zb * 1048576 + m * ldxt + n]);
                    ((bf16*)Cv)[(long)zb * sCb + (long)zh * sCh + m * ldc + n] = __float2bfloat16(g * v + xv);
                } else if constexpr (MODE == 4) {
                    v += bias[n];
                    v = v > 0.f ? v : 0.f;
                    ((bf16*)Cv)[m * ldc + n] = __float2bfloat16(v);
                } else {  // MODE 5: m local = bb*8192 + h*1024 + t (bb within pass)
                    v += bias[n];
                    v = v > 0.f ? v : 0.f;
                    long bb = m >> 13, h = (m >> 10) & 7, t = m & 1023;
                    long oi = bb * 1048576 + (n * 8 + h) * 1024 + t;
                    ((float*)Cv)[oi] = v + xf[oi];
                }
            }
        }
    }
}

// Fused energy + softmax. Grid: (slices, T/32). Block 256 (4 waves).
__global__ __launch_bounds__(256, 2)
void attn_fused(const bf16* __restrict__ qk, bf16* __restrict__ attn)
{
    constexpr int PAD = 1032;
    __shared__ __align__(16) char smraw[40960];   // phase A: Q 8K + K 32K; phase B: Sbuf 33024B
    __shared__ float red[2][4][32];
    bf16* Qs = (bf16*)smraw;                  // [32][128]
    bf16* Ks = (bf16*)(smraw + 8192);         // [128][128]
    bf16* Sbuf = (bf16*)smraw;                // [16][PAD]

    const int z = blockIdx.x;
    const int zb = z >> 3, zh = z & 7;
    const int t0 = blockIdx.y * 32;
    const int tid = threadIdx.x, w = tid >> 6, lane = tid & 63;
    const int col = lane & 15, quad = lane >> 4;

    const bf16* Qbase = qk + ((long)zb * 1024 + t0) * 2048 + zh * 256;
    const bf16* Kbase = qk + (long)zb * 1024 * 2048 + zh * 256 + 128;

    #pragma unroll
    for (int i = 0; i < 2; ++i) {
        int cbase = i * 256 + w * 64;
        int c = cbase + lane;
        int m = c >> 4, j = c & 15;
        __builtin_amdgcn_global_load_lds(
            (gvoid*)(Qbase + (long)m * 2048 + ((j ^ (m & 7)) << 3)),
            (lvoid*)(Qs + cbase * 8), 16, 0, 0);
    }
    __syncthreads();
    bf16x8 af[2][4];
    #pragma unroll
    for (int mi = 0; mi < 2; ++mi) {
        int m = mi * 16 + col;
        #pragma unroll
        for (int ki = 0; ki < 4; ++ki)
            af[mi][ki] = *(const bf16x8*)(Qs + m * 128 + ((((ki << 2) + quad) ^ (m & 7)) << 3));
    }

    f32x4 acc[2][16] = {};
    #pragma unroll
    for (int si = 0; si < 8; ++si) {
        __syncthreads();
        const bf16* Kb = Kbase + (long)si * 128 * 2048;
        #pragma unroll
        for (int i = 0; i < 8; ++i) {
            int cbase = i * 256 + w * 64;
            int c = cbase + lane;
            int m = c >> 4, j = c & 15;
            __builtin_amdgcn_global_load_lds(
                (gvoid*)(Kb + (long)m * 2048 + ((j ^ (m & 7)) << 3)),
                (lvoid*)(Ks + cbase * 8), 16, 0, 0);
        }
        __syncthreads();
        bf16x8 bfr[2][4];
        #pragma unroll
        for (int ni = 0; ni < 2; ++ni) {
            int n = w * 32 + ni * 16 + col;
            #pragma unroll
            for (int ki = 0; ki < 4; ++ki)
                bfr[ni][ki] = *(const bf16x8*)(Ks + n * 128 + ((((ki << 2) + quad) ^ (n & 7)) << 3));
        }
        #pragma unroll
        for (int ki = 0; ki < 4; ++ki)
            #pragma unroll
            for (int mi = 0; mi < 2; ++mi)
                #pragma unroll
                for (int ni = 0; ni < 2; ++ni)
                    acc[mi][si * 2 + ni] = __builtin_amdgcn_mfma_f32_16x16x32_bf16(
                        af[mi][ki], bfr[ni][ki], acc[mi][si * 2 + ni], 0, 0, 0);
    }

    float rmx[2][4], rinv[2][4];
    #pragma unroll
    for (int mi = 0; mi < 2; ++mi)
        #pragma unroll
        for (int r = 0; r < 4; ++r) {
            float mx = acc[mi][0][r];
            #pragma unroll
            for (int j = 1; j < 16; ++j) mx = fmaxf(mx, acc[mi][j][r]);
            #pragma unroll
            for (int off = 1; off < 16; off <<= 1) mx = fmaxf(mx, __shfl_xor(mx, off, 64));
            rmx[mi][r] = mx;
        }
    if (col == 0) {
        #pragma unroll
        for (int mi = 0; mi < 2; ++mi)
            #pragma unroll
            for (int r = 0; r < 4; ++r)
                red[0][w][mi * 16 + quad * 4 + r] = rmx[mi][r];
    }
    __syncthreads();
    #pragma unroll
    for (int mi = 0; mi < 2; ++mi)
        #pragma unroll
        for (int r = 0; r < 4; ++r) {
            int row = mi * 16 + quad * 4 + r;
            rmx[mi][r] = fmaxf(fmaxf(red[0][0][row], red[0][1][row]),
                               fmaxf(red[0][2][row], red[0][3][row]));
        }
    #pragma unroll
    for (int mi = 0; mi < 2; ++mi)
        #pragma unroll
        for (int r = 0; r < 4; ++r) {
            float s = 0.f;
            #pragma unroll
            for (int j = 0; j < 16; ++j) {
                acc[mi][j][r] = __expf(acc[mi][j][r] - rmx[mi][r]);
                s += acc[mi][j][r];
            }
            #pragma unroll
            for (int off = 1; off < 16; off <<= 1) s += __shfl_xor(s, off, 64);
            rinv[mi][r] = s;
        }
    if (col == 0) {
        #pragma unroll
        for (int mi = 0; mi < 2; ++mi)
            #pragma unroll
            for (int r = 0; r < 4; ++r)
                red[1][w][mi * 16 + quad * 4 + r] = rinv[mi][r];
    }
    __syncthreads();
    #pragma unroll
    for (int mi = 0; mi < 2; ++mi)
        #pragma unroll
        for (int r = 0; r < 4; ++r) {
            int row = mi * 16 + quad * 4 + r;
            float s4 = red[1][0][row] + red[1][1][row] + red[1][2][row] + red[1][3][row];
            rinv[mi][r] = 1.0f / s4;
        }

    bf16* dst = attn + ((long)(zb * 8 + zh)) * 1048576 + (long)t0 * 1024;
    #pragma unroll
    for (int mi = 0; mi < 2; ++mi) {
        __syncthreads();
        #pragma unroll
        for (int j = 0; j < 16; ++j) {
            int colb = (j >> 1) * 128 + w * 32 + (j & 1) * 16 + col;
            #pragma unroll
            for (int r = 0; r < 4; ++r) {
                int rowh = quad * 4 + r;
                Sbuf[rowh * PAD + colb] = __float2bfloat16(acc[mi][j][r] * rinv[mi][r]);
            }
        }
        __syncthreads();
        #pragma unroll
        for (int i = 0; i < 8; ++i) {
            int c = i * 256 + tid;             // 16 rows x 128 chunks
            int rowh = c >> 7, jj = c & 127;
            bf16x8 vv = *(const bf16x8*)(Sbuf + rowh * PAD + jj * 8);
            *(bf16x8*)(dst + (long)(mi * 16 + rowh) * 1024 + jj * 8) = vv;
        }
    }
}

// x (B,C,T) f32 -> xt (B,T,C) bf16, 32x32 LDS tiles
__global__ __launch_bounds__(256)
void transpose_cast_x(const float* __restrict__ x, bf16* __restrict__ xt)
{
    __shared__ float tile[32][33];
    int b = blockIdx.z;
    int c0 = blockIdx.y * 32, t0 = blockIdx.x * 32;
    int tx = threadIdx.x & 31, ty = threadIdx.x >> 5;  // ty 0..7
    const float* xb = x + (long)b * 1024 * 1024;
    #pragma unroll
    for (int i = 0; i < 4; ++i) {
        int c = ty + i * 8;
        tile[c][tx] = xb[(long)(c0 + c) * 1024 + t0 + tx];
    }
    __syncthreads();
    bf16* xtb = xt + (long)b * 1024 * 1024;
    #pragma unroll
    for (int i = 0; i < 4; ++i) {
        int t = ty + i * 8;
        xtb[(long)(t0 + t) * 1024 + c0 + tx] = __float2bfloat16(tile[tx][t]);
    }
}

__global__ __launch_bounds__(256)
void cast_f2b(const float* __restrict__ in, bf16* __restrict__ out, long n)
{
    long i = (long)blockIdx.x * 256 + threadIdx.x;
    long stride = (long)gridDim.x * 256;
    for (; i < n; i += stride) out[i] = __float2bfloat16(in[i]);
}

// Build stacked qk weight (2048 x 1024 bf16)
__global__ __launch_bounds__(256)
void build_wqk(const float* __restrict__ Wq, const float* __restrict__ Wk,
               const float* __restrict__ bq, const float* __restrict__ bk,
               bf16* __restrict__ Wqk, float* __restrict__ biasqk)
{
    long i = (long)blockIdx.x * 256 + threadIdx.x;   // 2048*1024 total
    long r = i >> 10, c = i & 1023;
    long h = r >> 8, rr = r & 255;
    float v = (rr < 128) ? Wq[(h * 128 + rr) * 1024 + c]
                         : Wk[(h * 128 + (rr - 128)) * 1024 + c];
    Wqk[i] = __float2bfloat16(v);
    if (c == 0)
        biasqk[r] = (rr < 128) ? bq[h * 128 + rr] : bk[h * 128 + rr - 128];
}

extern "C" void kernel_launch(void* const* d_in, const int* in_sizes, int n_in,
                              void* d_out, int out_size, void* d_ws, size_t ws_size,
                              hipStream_t stream)
{
    const float* x     = (const float*)d_in[0];
    const float* Wq    = (const float*)d_in[1];
    const float* bq    = (const float*)d_in[2];
    const float* Wk    = (const float*)d_in[3];
    const float* bk    = (const float*)d_in[4];
    const float* Wv    = (const float*)d_in[5];
    const float* bv    = (const float*)d_in[6];
    const float* gamma = (const float*)d_in[7];
    const float* W1    = (const float*)d_in[8];
    const float* b1    = (const float*)d_in[9];
    const float* W2    = (const float*)d_in[10];
    const float* b2    = (const float*)d_in[11];
    float* out = (float*)d_out;

    // chunk=4, two passes. Workspace (256 MiB exactly), MiB offsets:
    // [0,16)    xt            (live whole run)
    // [16,32)   Wvb           (live through pass-2 v-proj)
    // [32,96)   vbuf (pass)   — Wqk@[32,36) + bqk@[36,..) overlay, dead before pass-1 v
    // [96,160)  attb (pass)   — post-O per pass: W1b@96, W2b@96+0.5M, y1c@[97,105)
    // [160,224) ot   (pass)
    // [224,256) qkt           (live through pass-2 attn_fused)
    char* base = (char*)d_ws;
    const long MB = 1048576;
    bf16*  xt   = (bf16*)(base);
    bf16*  Wvb  = (bf16*)(base + 16 * MB);
    bf16*  vbuf = (bf16*)(base + 32 * MB);
    bf16*  Wqk  = (bf16*)(base + 32 * MB);          // dead after qk-proj
    float* bqk  = (float*)(base + 36 * MB);         // dead after qk-proj
    bf16*  attb = (bf16*)(base + 96 * MB);
    bf16*  W1b  = (bf16*)(base + 96 * MB);          // post-O overlay, re-cast per pass
    bf16*  W2b  = (bf16*)(base + 96 * MB + 524288);
    bf16*  y1c  = (bf16*)(base + 97 * MB);          // 8 MiB per pass
    bf16*  ot   = (bf16*)(base + 160 * MB);
    bf16*  qkt  = (bf16*)(base + 224 * MB);

    dim3 blk(256);
    transpose_cast_x<<<dim3(32, 32, 8), blk, 0, stream>>>(x, xt);
    build_wqk<<<8192, blk, 0, stream>>>(Wq, Wk, bq, bk, Wqk, bqk);
    cast_f2b<<<4096, blk, 0, stream>>>(Wv, Wvb, 8192ll * 1024);

    const long M1 = 1048576, M2 = 2097152, M8 = 8388608;

    // qk_t: M=8192 (b,t), N=2048 (h*256+o), K=1024 — full batch
    gemm_nt<1, 64, false><<<dim3(16, 64, 1), blk, 0, stream>>>(
        xt, 1024, 0, 0, Wqk, 1024, 0, 0, qkt, 2048, 0, 0, 1024,
        bqk, 0, nullptr, nullptr, 0, nullptr);

    for (int q = 0; q < 2; ++q) {
        const long b0 = (long)q * 4;
        const bf16* xtq = xt + b0 * M1;
        // v(zb,zh;c,s) = Wv[zh](c,ci) . xt(b0+zb;s,ci)^T + bv[zh,c]
        // 32 slices -> 2048 blocks (8/CU); zh == blockIdx.x%8 pins Wv[zh] per XCD
        gemm_nt<0, 64, true><<<dim3(32, 8, 8), blk, 0, stream>>>(
            Wvb, 1024, 0, M1, xtq, 1024, M1, 0, vbuf, 1024, M8, M1, 1024,
            bv, 1024, nullptr, nullptr, 0, nullptr);
        // fused E + softmax -> attb bf16 (1024 blocks)
        attn_fused<<<dim3(32, 32, 1), blk, 0, stream>>>(
            qkt + b0 * M2, attb);
        // heads_t(zb,zh;t,c) = gamma[zh]*(attn(t,s).v(c,s)^T) + xt(b0+zb;t,c)
        gemm_nt<3, 64, true><<<dim3(32, 8, 8), blk, 0, stream>>>(
            attb, 1024, M8, M1, vbuf, 1024, M8, M1,
            ot, 1024, M8, M1, 1024,
            nullptr, 0, gamma, xtq, 1024, nullptr);
        // attb dead: cast FC weights into its region (re-done each pass)
        cast_f2b<<<512, blk, 0, stream>>>(W1, W1b, 128 * 1024);
        cast_f2b<<<64, blk, 0, stream>>>(W2, W2b, 128 * 128);
        // y1c = relu(ot . W1^T + b1): M=32768, N=128, K=1024 (256 blocks, ot LLC-warm)
        gemm_nt<4, 64, false><<<dim3(1, 256, 1), blk, 0, stream>>>(
            ot, 1024, 0, 0, W1b, 1024, 0, 0, y1c, 128, 0, 0, 1024,
            b1, 0, nullptr, nullptr, 0, nullptr);
        // out = relu(y1c . W2^T + b2) scattered + x (pass-local rows)
        gemm_nt<5, 128, false><<<dim3(1, 256, 1), blk, 0, stream>>>(
            y1c, 128, 0, 0, W2b, 128, 0, 0, out + b0 * M1, 0, 0, 0, 128,
            b2, 0, nullptr, nullptr, 0, x + b0 * M1);
    }
}